// Round 12
// baseline (379.253 us; speedup 1.0000x reference)
//
#include <hip/hip_runtime.h>
#include <hip/hip_bf16.h>

// ---------------------------------------------------------------------------
// JKNet: 3x (bipartite SAGEConv(mean) + BN(eval) + ReLU) -> JK concat -> linear
//        -> log_softmax
// fp16 pipeline. CSR via bucket-hist + multisplit counting sort. Each layer is
// ONE fused kernel: phase A gathers neighbor means directly into the swizzled
// LDS A-tile; phase B runs the dual MFMA GEMM (agg half from LDS, x_dst half
// staged per k-step) with BN/ReLU fused and LDS-staged coalesced stores.
// ---------------------------------------------------------------------------

#define N_DST0 100000
#define N_DST1 50000
#define N_DST2 25000
#define HID 256
#define OUTC 47
#define ENDR 25000
#define DRC 512                         // dst nodes per CSR bucket
#define NBMAX 256                       // max coarse buckets
#define CHUNK 8192                      // edges per multisplit block
#define BN_SCALE 0.99999500003749969f   // rsqrt(1 + 1e-5)

#define SEL3(y, a, b, c) ((y) == 0 ? (a) : ((y) == 1 ? (b) : (c)))

typedef _Float16 f16x8 __attribute__((ext_vector_type(8)));
typedef _Float16 f16x4 __attribute__((ext_vector_type(4)));
typedef __attribute__((ext_vector_type(4))) float f32x4;

union U4H8 { uint4 u; f16x8 h; };

__device__ __forceinline__ f16x8 hshfl_add(f16x8 a, int m) {
    union { f16x8 h; int i[4]; } u, v;
    u.h = a;
#pragma unroll
    for (int j = 0; j < 4; ++j) v.i[j] = __shfl_xor(u.i[j], m);
    return a + v.h;
}

// ---------------------------------------------------------------------------
// fp32 -> fp16 conversion (n multiple of 4)
// ---------------------------------------------------------------------------
__global__ __launch_bounds__(256) void f2h_kernel(
    const float* __restrict__ in, _Float16* __restrict__ out, int n)
{
    int i = (blockIdx.x * 256 + threadIdx.x) * 4;
    if (i < n) {
        float4 v = *(const float4*)&in[i];
        f16x4 o = {(_Float16)v.x, (_Float16)v.y, (_Float16)v.z, (_Float16)v.w};
        *(f16x4*)&out[i] = o;
    }
}

// All 7 weight matrices + wlin zero-pad in one launch. Element boundaries:
// 0,32768,65536,131072,196608,262144,327680,363776; pad to 393216 (64x768).
__global__ __launch_bounds__(256) void f2h_multi(
    const float* s0, const float* s1, const float* s2, const float* s3,
    const float* s4, const float* s5, const float* s6,
    _Float16* d0, _Float16* d1, _Float16* d2, _Float16* d3,
    _Float16* d4, _Float16* d5, _Float16* d6)
{
    int idx = (blockIdx.x * 256 + threadIdx.x) * 4;
    const float* s; _Float16* d; int off;
    if (idx < 65536)       { if (idx < 32768)  { s = s0; d = d0; off = 0; }
                             else              { s = s1; d = d1; off = 32768; } }
    else if (idx < 196608) { if (idx < 131072) { s = s2; d = d2; off = 65536; }
                             else              { s = s3; d = d3; off = 131072; } }
    else if (idx < 327680) { if (idx < 262144) { s = s4; d = d4; off = 196608; }
                             else              { s = s5; d = d5; off = 262144; } }
    else if (idx < 363776) { s = s6; d = d6; off = 327680; }
    else if (idx < 393216) {  // zero pad of wlinb rows 47..63
        int j = idx - 327680;
        f16x4 z = {0, 0, 0, 0};
        *(f16x4*)&d6[j] = z;
        return;
    }
    else return;
    int j = idx - off;
    float4 v = *(const float4*)&s[j];
    f16x4 o = {(_Float16)v.x, (_Float16)v.y, (_Float16)v.z, (_Float16)v.w};
    *(f16x4*)&d[j] = o;
}

// ---------------------------------------------------------------------------
// Stage 1: coarse-bucket histogram (LDS; one padded global atomic per
// (block, nonzero bucket)).
// ---------------------------------------------------------------------------
__global__ __launch_bounds__(256) void bucket_hist_all(
    const int* c0, const int* c1, const int* c2,
    int* __restrict__ bhist, int E0, int E1, int E2)
{
    const int y = blockIdx.y;
    const int* col = SEL3(y, c0, c1, c2);
    const int E = SEL3(y, E0, E1, E2);
    __shared__ int h[NBMAX];
    const int t = threadIdx.x;
    h[t] = 0;
    __syncthreads();
    const int stride = gridDim.x * 256;
    for (int i = blockIdx.x * 256 + t; i < E; i += stride)
        atomicAdd(&h[col[i] >> 9], 1);
    __syncthreads();
    int v = h[t];
    if (v) atomicAdd(&bhist[(y * NBMAX + t) * 16], v);
}

// ---------------------------------------------------------------------------
// Stage 2: scan bucket counts -> bstart; seed multisplit cursors.
// ---------------------------------------------------------------------------
__global__ __launch_bounds__(256) void bucket_scan_all(
    const int* __restrict__ bhist, int* __restrict__ bstart,
    int* __restrict__ bcur)
{
    const int y = blockIdx.x;
    const int t = threadIdx.x;
    __shared__ int sh[256];
    int v = bhist[(y * NBMAX + t) * 16];
    sh[t] = v;
    __syncthreads();
    for (int off = 1; off < 256; off <<= 1) {
        int x = (t >= off) ? sh[t - off] : 0;
        __syncthreads();
        sh[t] += x;
        __syncthreads();
    }
    int ex = sh[t] - v;
    bstart[y * (NBMAX + 1) + t] = ex;
    if (t == 255) bstart[y * (NBMAX + 1) + 256] = sh[255];
    bcur[y * NBMAX * 16 + t * 16] = ex;
}

// ---------------------------------------------------------------------------
// Stage 3: LDS-staged multisplit; entries packed (c&511)<<18 | r.
// ---------------------------------------------------------------------------
__global__ __launch_bounds__(256) void multisplit_all(
    const int* r0, const int* r1, const int* r2,
    const int* c0, const int* c1, const int* c2,
    int* bcur, unsigned int* p0, unsigned int* p1, unsigned int* p2,
    int E0, int E1, int E2)
{
    const int y = blockIdx.y;
    const int E = SEL3(y, E0, E1, E2);
    const int base = blockIdx.x * CHUNK;
    if (base >= E) return;
    const int* row = SEL3(y, r0, r1, r2);
    const int* col = SEL3(y, c0, c1, c2);
    int* bc = bcur + y * (NBMAX * 16);
    unsigned int* part = SEL3(y, p0, p1, p2);

    __shared__ int hist[NBMAX];
    __shared__ int segoff[NBMAX + 1];
    __shared__ int cur[NBMAX];
    __shared__ int delta[NBMAX];
    __shared__ unsigned int stage[CHUNK];
    __shared__ unsigned char bstage[CHUNK];

    const int t = threadIdx.x;
    const int n = min(CHUNK, E - base);

    hist[t] = 0;
    __syncthreads();
    for (int i = t; i < n; i += 256)
        atomicAdd(&hist[col[base + i] >> 9], 1);
    __syncthreads();

    int v = hist[t];
    cur[t] = v;
    __syncthreads();
    for (int off = 1; off < 256; off <<= 1) {
        int x = (t >= off) ? cur[t - off] : 0;
        __syncthreads();
        cur[t] += x;
        __syncthreads();
    }
    segoff[t + 1] = cur[t];
    if (t == 0) segoff[0] = 0;
    __syncthreads();
    int so = segoff[t];
    cur[t] = so;
    if (v > 0) {
        int g = atomicAdd(&bc[t * 16], v);
        delta[t] = g - so;
    }
    __syncthreads();

    for (int i = t; i < n; i += 256) {
        int c = col[base + i];
        int r = row[base + i];
        int b = c >> 9;
        int p = atomicAdd(&cur[b], 1);
        stage[p] = ((unsigned)(c & 511) << 18) | (unsigned)r;
        bstage[p] = (unsigned char)b;
    }
    __syncthreads();

    for (int i = t; i < n; i += 256) {
        int b = bstage[i];
        part[delta[b] + i] = stage[i];
    }
}

// ---------------------------------------------------------------------------
// Stage 4: per-bucket CSR finalize (LDS hist + scan, coalesced deg/excl,
// LDS-cursor esrc fill).
// ---------------------------------------------------------------------------
__global__ __launch_bounds__(256) void bucket_csr_all(
    const unsigned int* p0, const unsigned int* p1, const unsigned int* p2,
    const int* __restrict__ bstart,
    int* g0, int* g1, int* g2, int* x0, int* x1, int* x2,
    int* s0, int* s1, int* s2, int n0, int n1, int n2)
{
    const int y = blockIdx.y;
    const int n_dst = SEL3(y, n0, n1, n2);
    const int b = blockIdx.x;
    const int d0 = b * DRC;
    if (d0 >= n_dst) return;
    const unsigned int* part = SEL3(y, p0, p1, p2);
    const int* bs = bstart + y * (NBMAX + 1);
    int* deg  = SEL3(y, g0, g1, g2);
    int* excl = SEL3(y, x0, x1, x2);
    int* esrc = SEL3(y, s0, s1, s2);

    __shared__ int h[DRC];
    __shared__ int cur2[DRC];
    __shared__ int tsum[256];
    const int t = threadIdx.x;
    h[t] = 0; h[t + 256] = 0;
    __syncthreads();
    const int wstart = bs[b], wend = bs[b + 1];
    for (int i = wstart + t; i < wend; i += 256)
        atomicAdd(&h[part[i] >> 18], 1);
    __syncthreads();

    int h0 = h[2 * t], h1 = h[2 * t + 1];
    int ps = h0 + h1;
    tsum[t] = ps;
    __syncthreads();
    for (int off = 1; off < 256; off <<= 1) {
        int x = (t >= off) ? tsum[t - off] : 0;
        __syncthreads();
        tsum[t] += x;
        __syncthreads();
    }
    int exp_ = tsum[t] - ps;
    cur2[2 * t]     = wstart + exp_;
    cur2[2 * t + 1] = wstart + exp_ + h0;
    __syncthreads();

    for (int j = t; j < DRC; j += 256) {
        int d = d0 + j;
        if (d < n_dst) { deg[d] = h[j]; excl[d] = cur2[j]; }
    }
    __syncthreads();

    for (int i = wstart + t; i < wend; i += 256) {
        unsigned int v = part[i];
        int pos = atomicAdd(&cur2[v >> 18], 1);
        esrc[pos] = (int)(v & 0x3FFFFu);
    }
}

// ---------------------------------------------------------------------------
// FUSED layer kernel: gather-mean into the swizzled LDS A-tile (phase A),
// then dual MFMA GEMM h = relu((agg.Wl^T + xdst.Wr^T)*BN_SCALE*g + b) with
// the agg half read from LDS and the xdst half staged per k-step (phase B).
// 512 threads = 8 waves. KH=128: TM=128 (waves 2Mx4N); KH=256: TM=64 (1Mx8N).
// ---------------------------------------------------------------------------
template<int KH, int TM>
__global__ __launch_bounds__(512) void fused_sage(
    const _Float16* __restrict__ xfeat,   // src & dst features [n_src][KH]
    const int* __restrict__ esrc, const int* __restrict__ excl,
    const int* __restrict__ deg,
    const _Float16* __restrict__ Wlb, const _Float16* __restrict__ Wrb,
    const float* __restrict__ g, const float* __restrict__ b,
    _Float16* __restrict__ h, int n_dst)
{
    constexpr int G    = KH / 8;             // uint4 groups per A row
    constexpr int NWN  = (TM == 128) ? 4 : 8;  // waves along N
    constexpr int NPW  = 256 / NWN;          // cols per wave (64 / 32)
    constexpr int NF   = NPW / 16;           // n-frags per wave (4 / 2)
    constexpr int AGGU = TM * G;             // 2048 uint4 = 32 KB both configs
    constexpr int SUBS = (KH == 128) ? 4 : 2;  // edge subgroups per wave
    constexpr int RL   = 64 / SUBS;          // lanes per row (16 / 32)
    constexpr int DPW  = TM / 8;             // dsts gathered per wave

    __shared__ uint4 SH[AGGU + 1024 + TM * 4];
    uint4* Agg_sh = SH;                      // [TM][G] swizzled
    uint4* B_sh   = SH + AGGU;               // [256][4] per k-step
    uint4* Axd_sh = SH + AGGU + 1024;        // [TM][4] per k-step

    const int tid  = threadIdx.x;
    const int lane = tid & 63;
    const int wv   = tid >> 6;
    const int m0g  = blockIdx.x * TM;

    // ---------------- Phase A: gather-mean into Agg_sh ----------------
    {
        const int sub = lane / RL;
        const int cl  = lane % RL;
        const size_t coff = (size_t)cl * 8;
        int sj = 0, dj = 0;
        {
            int m = m0g + wv * DPW + lane;
            if (lane < DPW && m < n_dst) { sj = excl[m]; dj = deg[m]; }
        }
        for (int j = 0; j < DPW; ++j) {
            int s = __shfl(sj, j);
            int d = __shfl(dj, j);
            f16x8 acc = {0, 0, 0, 0, 0, 0, 0, 0};
            int i = 0;
            for (; i + 4 * SUBS <= d; i += 4 * SUBS) {
                int e0 = esrc[s + i + sub];
                int e1 = esrc[s + i + SUBS + sub];
                int e2 = esrc[s + i + 2 * SUBS + sub];
                int e3 = esrc[s + i + 3 * SUBS + sub];
                f16x8 v0 = *(const f16x8*)&xfeat[((size_t)e0 << (KH == 128 ? 7 : 8)) + coff];
                f16x8 v1 = *(const f16x8*)&xfeat[((size_t)e1 << (KH == 128 ? 7 : 8)) + coff];
                f16x8 v2 = *(const f16x8*)&xfeat[((size_t)e2 << (KH == 128 ? 7 : 8)) + coff];
                f16x8 v3 = *(const f16x8*)&xfeat[((size_t)e3 << (KH == 128 ? 7 : 8)) + coff];
                acc += v0; acc += v1; acc += v2; acc += v3;
            }
            for (; i + SUBS <= d; i += SUBS) {
                int e0 = esrc[s + i + sub];
                acc += *(const f16x8*)&xfeat[((size_t)e0 << (KH == 128 ? 7 : 8)) + coff];
            }
            if (i + sub < d) {
                int e0 = esrc[s + i + sub];
                acc += *(const f16x8*)&xfeat[((size_t)e0 << (KH == 128 ? 7 : 8)) + coff];
            }
            if (KH == 128) { acc = hshfl_add(acc, 16); acc = hshfl_add(acc, 32); }
            else           { acc = hshfl_add(acc, 32); }
            if (sub == 0) {
                float inv = 1.0f / (float)max(d, 1);
                U4H8 o;
#pragma unroll
                for (int q = 0; q < 8; ++q) o.h[q] = (_Float16)((float)acc[q] * inv);
                int mloc = wv * DPW + j;
                Agg_sh[mloc * G + (cl & ~3) + ((cl & 3) ^ ((mloc >> 1) & 3))] = o.u;
            }
        }
    }
    __syncthreads();

    // ---------------- Phase B: dual GEMM ----------------
    const int lrow = lane & 15;
    const int lgrp = lane >> 4;
    const int mh   = wv / NWN;               // 0/1 for TM=128; 0 for TM=64
    const int n0   = (wv % NWN) * NPW;

    f32x4 acc2[4][NF];
#pragma unroll
    for (int i = 0; i < 4; ++i)
#pragma unroll
        for (int j = 0; j < NF; ++j)
            acc2[i][j] = (f32x4){0.f, 0.f, 0.f, 0.f};

    for (int kp = 0; kp < 2 * KH; kp += 32) {
        const bool left = kp < KH;
        const _Float16* Bsrc = left ? Wlb : Wrb;
        const int kbase = left ? kp : kp - KH;

        // stage B: 256 rows x 32 k
        {
            int nb_ = tid >> 2, gq = tid & 3;
#pragma unroll
            for (int i2 = 0; i2 < 2; ++i2) {
                int n = nb_ + 128 * i2;
                uint4 v = *(const uint4*)&Bsrc[(size_t)n * KH + kbase + gq * 8];
                B_sh[n * 4 + (gq ^ ((n >> 1) & 3))] = v;
            }
        }
        // stage A (xdst half only)
        if (!left) {
            for (int idx = tid; idx < TM * 4; idx += 512) {
                int m = idx >> 2, gq = idx & 3;
                int r = m0g + m;
                uint4 v = {0, 0, 0, 0};
                if (r < n_dst) v = *(const uint4*)&xfeat[(size_t)r * KH + kbase + gq * 8];
                Axd_sh[m * 4 + (gq ^ ((m >> 1) & 3))] = v;
            }
        }
        __syncthreads();

        f16x8 av[4], bv[NF];
        const int kb4 = (kbase >> 3) & ~3;   // (kbase/32)*4
#pragma unroll
        for (int mf = 0; mf < 4; ++mf) {
            int m = mh * 64 + mf * 16 + lrow;
            if (left)
                av[mf] = *reinterpret_cast<const f16x8*>(
                    &Agg_sh[m * G + kb4 + (lgrp ^ ((m >> 1) & 3))]);
            else
                av[mf] = *reinterpret_cast<const f16x8*>(
                    &Axd_sh[m * 4 + (lgrp ^ ((m >> 1) & 3))]);
        }
#pragma unroll
        for (int nf = 0; nf < NF; ++nf) {
            int n = n0 + nf * 16 + lrow;
            bv[nf] = *reinterpret_cast<const f16x8*>(&B_sh[n * 4 + (lgrp ^ ((n >> 1) & 3))]);
        }
#pragma unroll
        for (int mf = 0; mf < 4; ++mf)
#pragma unroll
            for (int nf = 0; nf < NF; ++nf)
                acc2[mf][nf] = __builtin_amdgcn_mfma_f32_16x16x32_f16(
                    av[mf], bv[nf], acc2[mf][nf], 0, 0, 0);
        __syncthreads();
    }

    // Epilogue: BN + ReLU; stage 64-row groups in LDS, coalesced uint4 writes.
    unsigned short* C_sh = (unsigned short*)SH;
    constexpr int HALVES = TM / 64;
#pragma unroll
    for (int half = 0; half < HALVES; ++half) {
        __syncthreads();
        if (mh == half) {
#pragma unroll
            for (int nf = 0; nf < NF; ++nf) {
                int n = n0 + nf * 16 + lrow;
                float sc = g[n] * BN_SCALE;
                float bi = b[n];
#pragma unroll
                for (int mf = 0; mf < 4; ++mf) {
                    int mloc = mf * 16 + lgrp * 4;
#pragma unroll
                    for (int r = 0; r < 4; ++r) {
                        float vv = fmaxf(acc2[mf][nf][r] * sc + bi, 0.f);
                        _Float16 hv = (_Float16)vv;
                        C_sh[(mloc + r) * 264 + n] = *(unsigned short*)&hv;
                    }
                }
            }
        }
        __syncthreads();
        int mbase = m0g + half * 64;
        for (int idx = tid; idx < 2048; idx += 512) {
            int rr = idx >> 5, cc = idx & 31;
            int m = mbase + rr;
            if (m < n_dst)
                *(uint4*)&h[(size_t)m * HID + cc * 8] =
                    *(const uint4*)&C_sh[rr * 264 + cc * 8];
        }
    }
}

// ---------------------------------------------------------------------------
// Final layer via MFMA (fp16 inputs): z = [h0|h1|h2][:25000] @ WlinPad.T +
// blin (N padded to 64), fused log_softmax, fp32 out. Tile 128 x 64, 4 waves.
// ---------------------------------------------------------------------------
__global__ __launch_bounds__(256) void final_mfma(
    const _Float16* __restrict__ h0, const _Float16* __restrict__ h1,
    const _Float16* __restrict__ h2, const _Float16* __restrict__ wlinb,
    const float* __restrict__ blin, float* __restrict__ out)
{
    __shared__ uint4 A_sh[512];   // [m:128][g':4]
    __shared__ uint4 B_sh[256];   // [n:64][g':4]

    const int tid  = threadIdx.x;
    const int lane = tid & 63;
    const int wv   = tid >> 6;
    const int m0g  = blockIdx.x * 128;
    const int lrow = lane & 15;
    const int lgrp = lane >> 4;

    f32x4 acc[2][4];
#pragma unroll
    for (int i = 0; i < 2; ++i)
#pragma unroll
        for (int j = 0; j < 4; ++j)
            acc[i][j] = (f32x4){0.f, 0.f, 0.f, 0.f};

    for (int kp = 0; kp < 768; kp += 32) {
        const int seg = kp >> 8;
        const _Float16* hs = (seg == 0) ? h0 : (seg == 1) ? h1 : h2;
        const int kseg = kp & 255;

#pragma unroll
        for (int l = 0; l < 2; ++l) {
            int idx = tid + l * 256;
            int m = idx >> 2, gq = idx & 3;
            int r = m0g + m;
            uint4 v = {0, 0, 0, 0};
            if (r < ENDR) v = *(const uint4*)&hs[(size_t)r * HID + kseg + gq * 8];
            A_sh[m * 4 + (gq ^ ((m >> 1) & 3))] = v;
        }
        {
            int n = tid >> 2, gq = tid & 3;
            uint4 v = *(const uint4*)&wlinb[(size_t)n * 768 + kp + gq * 8];
            B_sh[n * 4 + (gq ^ ((n >> 1) & 3))] = v;
        }
        __syncthreads();

        f16x8 av[2], bv[4];
#pragma unroll
        for (int mf = 0; mf < 2; ++mf) {
            int m = wv * 32 + mf * 16 + lrow;
            av[mf] = *reinterpret_cast<const f16x8*>(&A_sh[m * 4 + (lgrp ^ ((m >> 1) & 3))]);
        }
#pragma unroll
        for (int nf = 0; nf < 4; ++nf) {
            int n = nf * 16 + lrow;
            bv[nf] = *reinterpret_cast<const f16x8*>(&B_sh[n * 4 + (lgrp ^ ((n >> 1) & 3))]);
        }
#pragma unroll
        for (int mf = 0; mf < 2; ++mf)
#pragma unroll
            for (int nf = 0; nf < 4; ++nf)
                acc[mf][nf] = __builtin_amdgcn_mfma_f32_16x16x32_f16(
                    av[mf], bv[nf], acc[mf][nf], 0, 0, 0);
        __syncthreads();
    }

    float bv4[4];
#pragma unroll
    for (int nf = 0; nf < 4; ++nf) {
        int n = nf * 16 + lrow;
        bv4[nf] = (n < OUTC) ? blin[n] : 0.f;
    }

#pragma unroll
    for (int mf = 0; mf < 2; ++mf) {
        float z[4][4];
        float rmax[4], rsum[4];
#pragma unroll
        for (int r = 0; r < 4; ++r) {
            float mx = -INFINITY;
#pragma unroll
            for (int nf = 0; nf < 4; ++nf) {
                int n = nf * 16 + lrow;
                float v = (n < OUTC) ? acc[mf][nf][r] + bv4[nf] : -INFINITY;
                z[r][nf] = v;
                mx = fmaxf(mx, v);
            }
            rmax[r] = mx;
        }
#pragma unroll
        for (int off = 8; off >= 1; off >>= 1)
#pragma unroll
            for (int r = 0; r < 4; ++r)
                rmax[r] = fmaxf(rmax[r], __shfl_xor(rmax[r], off));
#pragma unroll
        for (int r = 0; r < 4; ++r) {
            float s = 0.f;
#pragma unroll
            for (int nf = 0; nf < 4; ++nf)
                s += (z[r][nf] > -INFINITY) ? expf(z[r][nf] - rmax[r]) : 0.f;
            rsum[r] = s;
        }
#pragma unroll
        for (int off = 8; off >= 1; off >>= 1)
#pragma unroll
            for (int r = 0; r < 4; ++r)
                rsum[r] += __shfl_xor(rsum[r], off);

#pragma unroll
        for (int r = 0; r < 4; ++r) {
            int m = m0g + wv * 32 + mf * 16 + lgrp * 4 + r;
            if (m < ENDR) {
                float lg = rmax[r] + logf(rsum[r]);
#pragma unroll
                for (int nf = 0; nf < 4; ++nf) {
                    int n = nf * 16 + lrow;
                    if (n < OUTC) out[(size_t)m * OUTC + n] = z[r][nf] - lg;
                }
            }
        }
    }
}

// ---------------------------------------------------------------------------
extern "C" void kernel_launch(void* const* d_in, const int* in_sizes, int n_in,
                              void* d_out, int out_size, void* d_ws, size_t ws_size,
                              hipStream_t stream)
{
    const float* x    = (const float*)d_in[0];
    const int* rows[3] = {(const int*)d_in[1], (const int*)d_in[3], (const int*)d_in[5]};
    const int* cols[3] = {(const int*)d_in[2], (const int*)d_in[4], (const int*)d_in[6]};
    const float* Wl[3] = {(const float*)d_in[7],  (const float*)d_in[11], (const float*)d_in[15]};
    const float* Wr[3] = {(const float*)d_in[8],  (const float*)d_in[12], (const float*)d_in[16]};
    const float* gs[3] = {(const float*)d_in[9],  (const float*)d_in[13], (const float*)d_in[17]};
    const float* bs[3] = {(const float*)d_in[10], (const float*)d_in[14], (const float*)d_in[18]};
    const float* Wlin = (const float*)d_in[19];
    const float* blin = (const float*)d_in[20];
    float* out = (float*)d_out;

    const int E0 = in_sizes[1], E1 = in_sizes[3], E2 = in_sizes[5];

    // ----- workspace layout (bytes) -----
    char* base = (char*)d_ws;
    _Float16* xb   = (_Float16*)(base);
    _Float16* h0b  = (_Float16*)(base + 51200000);
    _Float16* h1b  = (_Float16*)(base + 102400000);
    _Float16* h2b  = (_Float16*)(base + 128000000);
    _Float16* wb   = (_Float16*)(base + 166400000);
    _Float16* wlinb= (_Float16*)(base + 167100032);
    int* ibase = (int*)(base + 167600000);
    int* esrc0 = ibase;                 // 1.6M
    int* esrc1 = ibase + 1600000;       // 0.8M
    int* esrc2 = ibase + 2400000;       // 0.4M
    int* deg0  = ibase + 2800000;
    int* deg1  = ibase + 2900000;
    int* deg2  = ibase + 2950000;
    int* excl0 = ibase + 3000000;
    int* excl1 = ibase + 3100000;
    int* excl2 = ibase + 3150000;
    int* bcur  = ibase + 3200000;       // 3*NBMAX*16 = 12288
    int* bhist = ibase + 3220000;       // 3*NBMAX*16 = 12288
    int* bstart= ibase + 3240000;       // 3*(NBMAX+1) = 771
    unsigned int* part0 = (unsigned int*)(base + 181000000);
    unsigned int* part1 = (unsigned int*)(base + 188000000);
    unsigned int* part2 = (unsigned int*)(base + 192000000);

    _Float16* Wlb[3] = {wb,          wb + 65536,  wb + 196608};
    _Float16* Wrb[3] = {wb + 32768,  wb + 131072, wb + 262144};

    // ----- dtype conversions (wlin pad fused into f2h_multi) -----
    f2h_kernel<<<(25600000 / 4 + 255) / 256, 256, 0, stream>>>(x, xb, 25600000);
    f2h_multi<<<384, 256, 0, stream>>>(
        Wl[0], Wr[0], Wl[1], Wr[1], Wl[2], Wr[2], Wlin,
        Wlb[0], Wrb[0], Wlb[1], Wrb[1], Wlb[2], Wrb[2], wlinb);

    // ----- CSR build (4 launches + 1 small memset) -----
    hipMemsetAsync(bhist, 0, 3 * NBMAX * 16 * sizeof(int), stream);
    {
        dim3 gh(128, 3);
        bucket_hist_all<<<gh, 256, 0, stream>>>(
            cols[0], cols[1], cols[2], bhist, E0, E1, E2);
        bucket_scan_all<<<3, 256, 0, stream>>>(bhist, bstart, bcur);
        dim3 gms((E0 + CHUNK - 1) / CHUNK, 3);
        multisplit_all<<<gms, 256, 0, stream>>>(
            rows[0], rows[1], rows[2], cols[0], cols[1], cols[2],
            bcur, part0, part1, part2, E0, E1, E2);
        dim3 gbc((N_DST0 + DRC - 1) / DRC, 3);
        bucket_csr_all<<<gbc, 256, 0, stream>>>(
            part0, part1, part2, bstart,
            deg0, deg1, deg2, excl0, excl1, excl2,
            esrc0, esrc1, esrc2, N_DST0, N_DST1, N_DST2);
    }

    // ----- 3 fused layers -----
    fused_sage<128, 128><<<(N_DST0 + 127) / 128, 512, 0, stream>>>(
        xb, esrc0, excl0, deg0, Wlb[0], Wrb[0], gs[0], bs[0], h0b, N_DST0);
    fused_sage<256, 64><<<(N_DST1 + 63) / 64, 512, 0, stream>>>(
        h0b, esrc1, excl1, deg1, Wlb[1], Wrb[1], gs[1], bs[1], h1b, N_DST1);
    fused_sage<256, 64><<<(N_DST2 + 63) / 64, 512, 0, stream>>>(
        h1b, esrc2, excl2, deg2, Wlb[2], Wrb[2], gs[2], bs[2], h2b, N_DST2);

    final_mfma<<<(ENDR + 127) / 128, 256, 0, stream>>>(
        h0b, h1b, h2b, wlinb, blin, out);
}

// Round 13
// 374.156 us; speedup vs baseline: 1.0136x; 1.0136x over previous
//
#include <hip/hip_runtime.h>
#include <hip/hip_bf16.h>

// ---------------------------------------------------------------------------
// JKNet: 3x (bipartite SAGEConv(mean) + BN(eval) + ReLU) -> JK concat -> linear
//        -> log_softmax
// fp16 internal pipeline: CSR via bucket-hist + multisplit counting sort,
// packed-fp16 gather (deep-MLP, memory-system-bound), fp16 MFMA GEMMs with
// LDS-staged coalesced epilogue (BN/ReLU fused), fused log_softmax final.
// R13: revert of the R12 fusion experiment (occupancy loss > traffic saved).
// ---------------------------------------------------------------------------

#define N_DST0 100000
#define N_DST1 50000
#define N_DST2 25000
#define HID 256
#define OUTC 47
#define ENDR 25000
#define DRC 512                         // dst nodes per coarse bucket
#define NBMAX 256                       // max coarse buckets (100000/512=196)
#define CHUNK 8192                      // edges per multisplit block
#define BN_SCALE 0.99999500003749969f   // rsqrt(1 + 1e-5)

#define SEL3(y, a, b, c) ((y) == 0 ? (a) : ((y) == 1 ? (b) : (c)))

typedef _Float16 f16x8 __attribute__((ext_vector_type(8)));
typedef _Float16 f16x4 __attribute__((ext_vector_type(4)));
typedef __attribute__((ext_vector_type(4))) float f32x4;

__device__ __forceinline__ f16x8 hshfl_add(f16x8 a, int m) {
    union { f16x8 h; int i[4]; } u, v;
    u.h = a;
#pragma unroll
    for (int j = 0; j < 4; ++j) v.i[j] = __shfl_xor(u.i[j], m);
    return a + v.h;
}

// ---------------------------------------------------------------------------
// fp32 -> fp16 conversion (n multiple of 4)
// ---------------------------------------------------------------------------
__global__ __launch_bounds__(256) void f2h_kernel(
    const float* __restrict__ in, _Float16* __restrict__ out, int n)
{
    int i = (blockIdx.x * 256 + threadIdx.x) * 4;
    if (i < n) {
        float4 v = *(const float4*)&in[i];
        f16x4 o = {(_Float16)v.x, (_Float16)v.y, (_Float16)v.z, (_Float16)v.w};
        *(f16x4*)&out[i] = o;
    }
}

// All 7 weight matrices in one launch. Segment boundaries (elements):
// 0,32768,65536,131072,196608,262144,327680,363776 — all multiples of 4.
__global__ __launch_bounds__(256) void f2h_multi(
    const float* s0, const float* s1, const float* s2, const float* s3,
    const float* s4, const float* s5, const float* s6,
    _Float16* d0, _Float16* d1, _Float16* d2, _Float16* d3,
    _Float16* d4, _Float16* d5, _Float16* d6)
{
    int idx = (blockIdx.x * 256 + threadIdx.x) * 4;
    const float* s; _Float16* d; int off;
    if (idx < 65536)       { if (idx < 32768)  { s = s0; d = d0; off = 0; }
                             else              { s = s1; d = d1; off = 32768; } }
    else if (idx < 196608) { if (idx < 131072) { s = s2; d = d2; off = 65536; }
                             else              { s = s3; d = d3; off = 131072; } }
    else if (idx < 327680) { if (idx < 262144) { s = s4; d = d4; off = 196608; }
                             else              { s = s5; d = d5; off = 262144; } }
    else if (idx < 363776) { s = s6; d = d6; off = 327680; }
    else return;
    int j = idx - off;
    float4 v = *(const float4*)&s[j];
    f16x4 o = {(_Float16)v.x, (_Float16)v.y, (_Float16)v.z, (_Float16)v.w};
    *(f16x4*)&d[j] = o;
}

// ---------------------------------------------------------------------------
// Stage 1: coarse-bucket histogram (LDS; one padded global atomic per
// (block, nonzero bucket)).
// ---------------------------------------------------------------------------
__global__ __launch_bounds__(256) void bucket_hist_all(
    const int* c0, const int* c1, const int* c2,
    int* __restrict__ bhist, int E0, int E1, int E2)
{
    const int y = blockIdx.y;
    const int* col = SEL3(y, c0, c1, c2);
    const int E = SEL3(y, E0, E1, E2);
    __shared__ int h[NBMAX];
    const int t = threadIdx.x;
    h[t] = 0;
    __syncthreads();
    const int stride = gridDim.x * 256;
    for (int i = blockIdx.x * 256 + t; i < E; i += stride)
        atomicAdd(&h[col[i] >> 9], 1);
    __syncthreads();
    int v = h[t];
    if (v) atomicAdd(&bhist[(y * NBMAX + t) * 16], v);
}

// ---------------------------------------------------------------------------
// Stage 2: scan bucket counts -> bstart; seed multisplit cursors.
// ---------------------------------------------------------------------------
__global__ __launch_bounds__(256) void bucket_scan_all(
    const int* __restrict__ bhist, int* __restrict__ bstart,
    int* __restrict__ bcur)
{
    const int y = blockIdx.x;
    const int t = threadIdx.x;
    __shared__ int sh[256];
    int v = bhist[(y * NBMAX + t) * 16];
    sh[t] = v;
    __syncthreads();
    for (int off = 1; off < 256; off <<= 1) {
        int x = (t >= off) ? sh[t - off] : 0;
        __syncthreads();
        sh[t] += x;
        __syncthreads();
    }
    int ex = sh[t] - v;
    bstart[y * (NBMAX + 1) + t] = ex;
    if (t == 255) bstart[y * (NBMAX + 1) + 256] = sh[255];
    bcur[y * NBMAX * 16 + t * 16] = ex;
}

// ---------------------------------------------------------------------------
// Stage 3: LDS-staged multisplit; entries packed (c&511)<<18 | r.
// ---------------------------------------------------------------------------
__global__ __launch_bounds__(256) void multisplit_all(
    const int* r0, const int* r1, const int* r2,
    const int* c0, const int* c1, const int* c2,
    int* bcur, unsigned int* p0, unsigned int* p1, unsigned int* p2,
    int E0, int E1, int E2)
{
    const int y = blockIdx.y;
    const int E = SEL3(y, E0, E1, E2);
    const int base = blockIdx.x * CHUNK;
    if (base >= E) return;
    const int* row = SEL3(y, r0, r1, r2);
    const int* col = SEL3(y, c0, c1, c2);
    int* bc = bcur + y * (NBMAX * 16);
    unsigned int* part = SEL3(y, p0, p1, p2);

    __shared__ int hist[NBMAX];
    __shared__ int segoff[NBMAX + 1];
    __shared__ int cur[NBMAX];
    __shared__ int delta[NBMAX];
    __shared__ unsigned int stage[CHUNK];
    __shared__ unsigned char bstage[CHUNK];

    const int t = threadIdx.x;
    const int n = min(CHUNK, E - base);

    hist[t] = 0;
    __syncthreads();
    for (int i = t; i < n; i += 256)
        atomicAdd(&hist[col[base + i] >> 9], 1);
    __syncthreads();

    int v = hist[t];
    cur[t] = v;
    __syncthreads();
    for (int off = 1; off < 256; off <<= 1) {
        int x = (t >= off) ? cur[t - off] : 0;
        __syncthreads();
        cur[t] += x;
        __syncthreads();
    }
    segoff[t + 1] = cur[t];
    if (t == 0) segoff[0] = 0;
    __syncthreads();
    int so = segoff[t];
    cur[t] = so;
    if (v > 0) {
        int g = atomicAdd(&bc[t * 16], v);
        delta[t] = g - so;
    }
    __syncthreads();

    for (int i = t; i < n; i += 256) {
        int c = col[base + i];
        int r = row[base + i];
        int b = c >> 9;
        int p = atomicAdd(&cur[b], 1);
        stage[p] = ((unsigned)(c & 511) << 18) | (unsigned)r;
        bstage[p] = (unsigned char)b;
    }
    __syncthreads();

    for (int i = t; i < n; i += 256) {
        int b = bstage[i];
        part[delta[b] + i] = stage[i];
    }
}

// ---------------------------------------------------------------------------
// Stage 4: per-bucket CSR finalize (LDS hist + scan, coalesced deg/excl,
// LDS-cursor esrc fill).
// ---------------------------------------------------------------------------
__global__ __launch_bounds__(256) void bucket_csr_all(
    const unsigned int* p0, const unsigned int* p1, const unsigned int* p2,
    const int* __restrict__ bstart,
    int* g0, int* g1, int* g2, int* x0, int* x1, int* x2,
    int* s0, int* s1, int* s2, int n0, int n1, int n2)
{
    const int y = blockIdx.y;
    const int n_dst = SEL3(y, n0, n1, n2);
    const int b = blockIdx.x;
    const int d0 = b * DRC;
    if (d0 >= n_dst) return;
    const unsigned int* part = SEL3(y, p0, p1, p2);
    const int* bs = bstart + y * (NBMAX + 1);
    int* deg  = SEL3(y, g0, g1, g2);
    int* excl = SEL3(y, x0, x1, x2);
    int* esrc = SEL3(y, s0, s1, s2);

    __shared__ int h[DRC];
    __shared__ int cur2[DRC];
    __shared__ int tsum[256];
    const int t = threadIdx.x;
    h[t] = 0; h[t + 256] = 0;
    __syncthreads();
    const int wstart = bs[b], wend = bs[b + 1];
    for (int i = wstart + t; i < wend; i += 256)
        atomicAdd(&h[part[i] >> 18], 1);
    __syncthreads();

    int h0 = h[2 * t], h1 = h[2 * t + 1];
    int ps = h0 + h1;
    tsum[t] = ps;
    __syncthreads();
    for (int off = 1; off < 256; off <<= 1) {
        int x = (t >= off) ? tsum[t - off] : 0;
        __syncthreads();
        tsum[t] += x;
        __syncthreads();
    }
    int exp_ = tsum[t] - ps;
    cur2[2 * t]     = wstart + exp_;
    cur2[2 * t + 1] = wstart + exp_ + h0;
    __syncthreads();

    for (int j = t; j < DRC; j += 256) {
        int d = d0 + j;
        if (d < n_dst) { deg[d] = h[j]; excl[d] = cur2[j]; }
    }
    __syncthreads();

    for (int i = wstart + t; i < wend; i += 256) {
        unsigned int v = part[i];
        int pos = atomicAdd(&cur2[v >> 18], 1);
        esrc[pos] = (int)(v & 0x3FFFFu);
    }
}

// ---------------------------------------------------------------------------
// Gather-mean, fp16 packed accumulation, deep MLP.
// K=128: 4 subgroups x 16 lanes; K=256: 2 subgroups x 32 lanes.
// fp32-scaled mean, fp16 out. Memory-system-bound (6.7 TB/s effective).
// ---------------------------------------------------------------------------
template<int LOGK>
__global__ __launch_bounds__(256) void gather_mean(
    const _Float16* __restrict__ xsrc, const int* __restrict__ esrc,
    const int* __restrict__ start, const int* __restrict__ deg,
    _Float16* __restrict__ agg, int n_dst)
{
    const int wid = (blockIdx.x * 256 + threadIdx.x) >> 6;
    const int lane = threadIdx.x & 63;
    if (wid >= n_dst) return;
    const int s = start[wid];
    const int d = deg[wid];
    const float inv = 1.0f / (float)max(d, 1);
    f16x8 acc = {0, 0, 0, 0, 0, 0, 0, 0};

    if (LOGK == 7) {
        const int sub = lane >> 4;          // 4 subgroups x 16 lanes
        const int cl  = lane & 15;
        const size_t coff = (size_t)cl * 8;
        int i = 0;
        for (; i + 16 <= d; i += 16) {
            int e0 = esrc[s + i + sub],      e1 = esrc[s + i + 4 + sub];
            int e2 = esrc[s + i + 8 + sub],  e3 = esrc[s + i + 12 + sub];
            f16x8 v0 = *(const f16x8*)&xsrc[((size_t)e0 << 7) + coff];
            f16x8 v1 = *(const f16x8*)&xsrc[((size_t)e1 << 7) + coff];
            f16x8 v2 = *(const f16x8*)&xsrc[((size_t)e2 << 7) + coff];
            f16x8 v3 = *(const f16x8*)&xsrc[((size_t)e3 << 7) + coff];
            acc += v0; acc += v1; acc += v2; acc += v3;
        }
        for (; i + 4 <= d; i += 4) {
            int e0 = esrc[s + i + sub];
            acc += *(const f16x8*)&xsrc[((size_t)e0 << 7) + coff];
        }
        if (i + sub < d) {
            int e0 = esrc[s + i + sub];
            acc += *(const f16x8*)&xsrc[((size_t)e0 << 7) + coff];
        }
        acc = hshfl_add(acc, 16);
        acc = hshfl_add(acc, 32);
        if (sub == 0) {
            f16x8 o;
#pragma unroll
            for (int j = 0; j < 8; ++j) o[j] = (_Float16)((float)acc[j] * inv);
            *(f16x8*)&agg[((size_t)wid << 7) + coff] = o;
        }
    } else {
        const int sub = lane >> 5;          // 2 subgroups x 32 lanes
        const int cl  = lane & 31;
        const size_t coff = (size_t)cl * 8;
        int i = 0;
        for (; i + 16 <= d; i += 16) {
            int e0 = esrc[s + i + sub],      e1 = esrc[s + i + 2 + sub];
            int e2 = esrc[s + i + 4 + sub],  e3 = esrc[s + i + 6 + sub];
            int e4 = esrc[s + i + 8 + sub],  e5 = esrc[s + i + 10 + sub];
            int e6 = esrc[s + i + 12 + sub], e7 = esrc[s + i + 14 + sub];
            f16x8 v0 = *(const f16x8*)&xsrc[((size_t)e0 << 8) + coff];
            f16x8 v1 = *(const f16x8*)&xsrc[((size_t)e1 << 8) + coff];
            f16x8 v2 = *(const f16x8*)&xsrc[((size_t)e2 << 8) + coff];
            f16x8 v3 = *(const f16x8*)&xsrc[((size_t)e3 << 8) + coff];
            f16x8 v4 = *(const f16x8*)&xsrc[((size_t)e4 << 8) + coff];
            f16x8 v5 = *(const f16x8*)&xsrc[((size_t)e5 << 8) + coff];
            f16x8 v6 = *(const f16x8*)&xsrc[((size_t)e6 << 8) + coff];
            f16x8 v7 = *(const f16x8*)&xsrc[((size_t)e7 << 8) + coff];
            acc += v0; acc += v1; acc += v2; acc += v3;
            acc += v4; acc += v5; acc += v6; acc += v7;
        }
        for (; i + 2 <= d; i += 2) {
            int e0 = esrc[s + i + sub];
            acc += *(const f16x8*)&xsrc[((size_t)e0 << 8) + coff];
        }
        if (i + sub < d) {
            int e0 = esrc[s + i + sub];
            acc += *(const f16x8*)&xsrc[((size_t)e0 << 8) + coff];
        }
        acc = hshfl_add(acc, 32);
        if (sub == 0) {
            f16x8 o;
#pragma unroll
            for (int j = 0; j < 8; ++j) o[j] = (_Float16)((float)acc[j] * inv);
            *(f16x8*)&agg[((size_t)wid << 8) + coff] = o;
        }
    }
}

// ---------------------------------------------------------------------------
// fp16 MFMA GEMM: h = relu((agg.Wl^T + xdst.Wr^T) * BN_SCALE * g + b), fp16 out
// Block: 512 threads = 8 waves (2 M-halves x 4 N-quarters). Tile 128 x 256.
// Epilogue staged through LDS (2 passes of 64 rows) -> coalesced uint4 writes.
// ---------------------------------------------------------------------------
template<int KH>
__global__ __launch_bounds__(512) void sage_gemm_mfma(
    const _Float16* __restrict__ aggb, const _Float16* __restrict__ xdstb,
    const _Float16* __restrict__ Wlb, const _Float16* __restrict__ Wrb,
    const float* __restrict__ g, const float* __restrict__ b,
    _Float16* __restrict__ h, int n_dst)
{
    __shared__ uint4 SH[2176];     // 34,816 B: A[512] | B[1024]; reused as C-stage
    uint4* A_sh = SH;
    uint4* B_sh = SH + 512;

    const int tid  = threadIdx.x;
    const int lane = tid & 63;
    const int wv   = tid >> 6;
    const int mh   = wv >> 2;
    const int n0   = (wv & 3) * 64;
    const int m0g  = blockIdx.x * 128;
    const int lrow = lane & 15;
    const int lgrp = lane >> 4;

    f32x4 acc[4][4];
#pragma unroll
    for (int i = 0; i < 4; ++i)
#pragma unroll
        for (int j = 0; j < 4; ++j)
            acc[i][j] = (f32x4){0.f, 0.f, 0.f, 0.f};

    for (int kp = 0; kp < 2 * KH; kp += 32) {
        const _Float16* Asrc = (kp < KH) ? aggb : xdstb;
        const _Float16* Bsrc = (kp < KH) ? Wlb : Wrb;
        const int kbase = (kp < KH) ? kp : kp - KH;

        {
            int m = tid >> 2, gq = tid & 3;
            int r = m0g + m;
            uint4 v = {0, 0, 0, 0};
            if (r < n_dst) v = *(const uint4*)&Asrc[(size_t)r * KH + kbase + gq * 8];
            A_sh[m * 4 + (gq ^ ((m >> 1) & 3))] = v;
        }
        {
            int nb_ = tid >> 2, gq = tid & 3;
#pragma unroll
            for (int i2 = 0; i2 < 2; ++i2) {
                int n = nb_ + 128 * i2;
                uint4 v = *(const uint4*)&Bsrc[(size_t)n * KH + kbase + gq * 8];
                B_sh[n * 4 + (gq ^ ((n >> 1) & 3))] = v;
            }
        }
        __syncthreads();

        f16x8 av[4], bv[4];
#pragma unroll
        for (int mf = 0; mf < 4; ++mf) {
            int m = mh * 64 + mf * 16 + lrow;
            av[mf] = *reinterpret_cast<const f16x8*>(&A_sh[m * 4 + (lgrp ^ ((m >> 1) & 3))]);
        }
#pragma unroll
        for (int nf = 0; nf < 4; ++nf) {
            int n = n0 + nf * 16 + lrow;
            bv[nf] = *reinterpret_cast<const f16x8*>(&B_sh[n * 4 + (lgrp ^ ((n >> 1) & 3))]);
        }
#pragma unroll
        for (int mf = 0; mf < 4; ++mf)
#pragma unroll
            for (int nf = 0; nf < 4; ++nf)
                acc[mf][nf] = __builtin_amdgcn_mfma_f32_16x16x32_f16(
                    av[mf], bv[nf], acc[mf][nf], 0, 0, 0);
        __syncthreads();
    }

    // Epilogue: BN + ReLU; stage each 64-row half in LDS [64][264] ushorts,
    // then fully-coalesced uint4 row writes. C/D: col=lane&15, row=(lane>>4)*4+reg.
    unsigned short* C_sh = (unsigned short*)SH;
#pragma unroll
    for (int half = 0; half < 2; ++half) {
        __syncthreads();
        if (mh == half) {
#pragma unroll
            for (int nf = 0; nf < 4; ++nf) {
                int n = n0 + nf * 16 + lrow;
                float sc = g[n] * BN_SCALE;
                float bi = b[n];
#pragma unroll
                for (int mf = 0; mf < 4; ++mf) {
                    int mloc = mf * 16 + lgrp * 4;
#pragma unroll
                    for (int r = 0; r < 4; ++r) {
                        float vv = fmaxf(acc[mf][nf][r] * sc + bi, 0.f);
                        _Float16 hv = (_Float16)vv;
                        C_sh[(mloc + r) * 264 + n] = *(unsigned short*)&hv;
                    }
                }
            }
        }
        __syncthreads();
        int mbase = m0g + half * 64;
#pragma unroll
        for (int k = 0; k < 4; ++k) {
            int idx = tid + k * 512;
            int rr = idx >> 5, cc = idx & 31;
            int m = mbase + rr;
            if (m < n_dst)
                *(uint4*)&h[(size_t)m * HID + cc * 8] =
                    *(const uint4*)&C_sh[rr * 264 + cc * 8];
        }
    }
}

// ---------------------------------------------------------------------------
// Final layer via MFMA (fp16 inputs): z = [h0|h1|h2][:25000] @ WlinPad.T +
// blin (N padded to 64), fused log_softmax, fp32 out. Tile 128 x 64, 4 waves.
// ---------------------------------------------------------------------------
__global__ __launch_bounds__(256) void final_mfma(
    const _Float16* __restrict__ h0, const _Float16* __restrict__ h1,
    const _Float16* __restrict__ h2, const _Float16* __restrict__ wlinb,
    const float* __restrict__ blin, float* __restrict__ out)
{
    __shared__ uint4 A_sh[512];   // [m:128][g':4]
    __shared__ uint4 B_sh[256];   // [n:64][g':4]

    const int tid  = threadIdx.x;
    const int lane = tid & 63;
    const int wv   = tid >> 6;
    const int m0g  = blockIdx.x * 128;
    const int lrow = lane & 15;
    const int lgrp = lane >> 4;

    f32x4 acc[2][4];
#pragma unroll
    for (int i = 0; i < 2; ++i)
#pragma unroll
        for (int j = 0; j < 4; ++j)
            acc[i][j] = (f32x4){0.f, 0.f, 0.f, 0.f};

    for (int kp = 0; kp < 768; kp += 32) {
        const int seg = kp >> 8;
        const _Float16* hs = (seg == 0) ? h0 : (seg == 1) ? h1 : h2;
        const int kseg = kp & 255;

#pragma unroll
        for (int l = 0; l < 2; ++l) {
            int idx = tid + l * 256;
            int m = idx >> 2, gq = idx & 3;
            int r = m0g + m;
            uint4 v = {0, 0, 0, 0};
            if (r < ENDR) v = *(const uint4*)&hs[(size_t)r * HID + kseg + gq * 8];
            A_sh[m * 4 + (gq ^ ((m >> 1) & 3))] = v;
        }
        {
            int n = tid >> 2, gq = tid & 3;
            uint4 v = *(const uint4*)&wlinb[(size_t)n * 768 + kp + gq * 8];
            B_sh[n * 4 + (gq ^ ((n >> 1) & 3))] = v;
        }
        __syncthreads();

        f16x8 av[2], bv[4];
#pragma unroll
        for (int mf = 0; mf < 2; ++mf) {
            int m = wv * 32 + mf * 16 + lrow;
            av[mf] = *reinterpret_cast<const f16x8*>(&A_sh[m * 4 + (lgrp ^ ((m >> 1) & 3))]);
        }
#pragma unroll
        for (int nf = 0; nf < 4; ++nf) {
            int n = nf * 16 + lrow;
            bv[nf] = *reinterpret_cast<const f16x8*>(&B_sh[n * 4 + (lgrp ^ ((n >> 1) & 3))]);
        }
#pragma unroll
        for (int mf = 0; mf < 2; ++mf)
#pragma unroll
            for (int nf = 0; nf < 4; ++nf)
                acc[mf][nf] = __builtin_amdgcn_mfma_f32_16x16x32_f16(
                    av[mf], bv[nf], acc[mf][nf], 0, 0, 0);
        __syncthreads();
    }

    float bv4[4];
#pragma unroll
    for (int nf = 0; nf < 4; ++nf) {
        int n = nf * 16 + lrow;
        bv4[nf] = (n < OUTC) ? blin[n] : 0.f;
    }

#pragma unroll
    for (int mf = 0; mf < 2; ++mf) {
        float z[4][4];
        float rmax[4], rsum[4];
#pragma unroll
        for (int r = 0; r < 4; ++r) {
            float mx = -INFINITY;
#pragma unroll
            for (int nf = 0; nf < 4; ++nf) {
                int n = nf * 16 + lrow;
                float v = (n < OUTC) ? acc[mf][nf][r] + bv4[nf] : -INFINITY;
                z[r][nf] = v;
                mx = fmaxf(mx, v);
            }
            rmax[r] = mx;
        }
#pragma unroll
        for (int off = 8; off >= 1; off >>= 1)
#pragma unroll
            for (int r = 0; r < 4; ++r)
                rmax[r] = fmaxf(rmax[r], __shfl_xor(rmax[r], off));
#pragma unroll
        for (int r = 0; r < 4; ++r) {
            float s = 0.f;
#pragma unroll
            for (int nf = 0; nf < 4; ++nf)
                s += (z[r][nf] > -INFINITY) ? expf(z[r][nf] - rmax[r]) : 0.f;
            rsum[r] = s;
        }
#pragma unroll
        for (int off = 8; off >= 1; off >>= 1)
#pragma unroll
            for (int r = 0; r < 4; ++r)
                rsum[r] += __shfl_xor(rsum[r], off);

#pragma unroll
        for (int r = 0; r < 4; ++r) {
            int m = m0g + wv * 32 + mf * 16 + lgrp * 4 + r;
            if (m < ENDR) {
                float lg = rmax[r] + logf(rsum[r]);
#pragma unroll
                for (int nf = 0; nf < 4; ++nf) {
                    int n = nf * 16 + lrow;
                    if (n < OUTC) out[(size_t)m * OUTC + n] = z[r][nf] - lg;
                }
            }
        }
    }
}

// ---------------------------------------------------------------------------
extern "C" void kernel_launch(void* const* d_in, const int* in_sizes, int n_in,
                              void* d_out, int out_size, void* d_ws, size_t ws_size,
                              hipStream_t stream)
{
    const float* x    = (const float*)d_in[0];
    const int* rows[3] = {(const int*)d_in[1], (const int*)d_in[3], (const int*)d_in[5]};
    const int* cols[3] = {(const int*)d_in[2], (const int*)d_in[4], (const int*)d_in[6]};
    const float* Wl[3] = {(const float*)d_in[7],  (const float*)d_in[11], (const float*)d_in[15]};
    const float* Wr[3] = {(const float*)d_in[8],  (const float*)d_in[12], (const float*)d_in[16]};
    const float* gs[3] = {(const float*)d_in[9],  (const float*)d_in[13], (const float*)d_in[17]};
    const float* bs[3] = {(const float*)d_in[10], (const float*)d_in[14], (const float*)d_in[18]};
    const float* Wlin = (const float*)d_in[19];
    const float* blin = (const float*)d_in[20];
    float* out = (float*)d_out;

    const int E0 = in_sizes[1], E1 = in_sizes[3], E2 = in_sizes[5];

    // ----- workspace layout (bytes) -----
    char* base = (char*)d_ws;
    _Float16* xb   = (_Float16*)(base);
    _Float16* h0b  = (_Float16*)(base + 51200000);
    _Float16* h1b  = (_Float16*)(base + 102400000);
    _Float16* h2b  = (_Float16*)(base + 128000000);
    _Float16* aggb = (_Float16*)(base + 140800000);
    _Float16* wb   = (_Float16*)(base + 166400000);
    _Float16* wlinb= (_Float16*)(base + 167100032);
    int* ibase = (int*)(base + 167600000);
    int* esrc0 = ibase;                 // 1.6M
    int* esrc1 = ibase + 1600000;       // 0.8M
    int* esrc2 = ibase + 2400000;       // 0.4M
    int* deg0  = ibase + 2800000;
    int* deg1  = ibase + 2900000;
    int* deg2  = ibase + 2950000;
    int* excl0 = ibase + 3000000;
    int* excl1 = ibase + 3100000;
    int* excl2 = ibase + 3150000;
    int* bcur  = ibase + 3200000;       // 3*NBMAX*16 = 12288
    int* bhist = ibase + 3220000;       // 3*NBMAX*16 = 12288
    int* bstart= ibase + 3240000;       // 3*(NBMAX+1) = 771
    unsigned int* part0 = (unsigned int*)(base + 181000000);
    unsigned int* part1 = (unsigned int*)(base + 188000000);
    unsigned int* part2 = (unsigned int*)(base + 192000000);

    _Float16* Wlb[3] = {wb,          wb + 65536,  wb + 196608};
    _Float16* Wrb[3] = {wb + 32768,  wb + 131072, wb + 262144};

    // ----- dtype conversions -----
    f2h_kernel<<<(25600000 / 4 + 255) / 256, 256, 0, stream>>>(x, xb, 25600000);
    hipMemsetAsync(wlinb, 0, 64 * 768 * sizeof(_Float16), stream);
    f2h_multi<<<356, 256, 0, stream>>>(
        Wl[0], Wr[0], Wl[1], Wr[1], Wl[2], Wr[2], Wlin,
        Wlb[0], Wrb[0], Wlb[1], Wrb[1], Wlb[2], Wrb[2], wlinb);

    // ----- CSR build (4 launches + 1 small memset) -----
    hipMemsetAsync(bhist, 0, 3 * NBMAX * 16 * sizeof(int), stream);
    {
        dim3 gh(128, 3);
        bucket_hist_all<<<gh, 256, 0, stream>>>(
            cols[0], cols[1], cols[2], bhist, E0, E1, E2);
        bucket_scan_all<<<3, 256, 0, stream>>>(bhist, bstart, bcur);
        dim3 gms((E0 + CHUNK - 1) / CHUNK, 3);
        multisplit_all<<<gms, 256, 0, stream>>>(
            rows[0], rows[1], rows[2], cols[0], cols[1], cols[2],
            bcur, part0, part1, part2, E0, E1, E2);
        dim3 gbc((N_DST0 + DRC - 1) / DRC, 3);
        bucket_csr_all<<<gbc, 256, 0, stream>>>(
            part0, part1, part2, bstart,
            deg0, deg1, deg2, excl0, excl1, excl2,
            esrc0, esrc1, esrc2, N_DST0, N_DST1, N_DST2);
    }

    // ----- 3 layers: gather + fused GEMM -----
    const _Float16* hsrc[3] = {xb, h0b, h1b};
    _Float16* hdst[3] = {h0b, h1b, h2b};
    int* esrcs[3] = {esrc0, esrc1, esrc2};
    int* excls[3] = {excl0, excl1, excl2};
    int* degs[3]  = {deg0, deg1, deg2};
    const int ndst[3] = {N_DST0, N_DST1, N_DST2};

    for (int L = 0; L < 3; ++L) {
        const int nd = ndst[L];
        if (L == 0) {
            gather_mean<7><<<(nd + 3) / 4, 256, 0, stream>>>(
                hsrc[L], esrcs[L], excls[L], degs[L], aggb, nd);
            sage_gemm_mfma<128><<<(nd + 127) / 128, 512, 0, stream>>>(
                aggb, hsrc[L], Wlb[L], Wrb[L], gs[L], bs[L], hdst[L], nd);
        } else {
            gather_mean<8><<<(nd + 3) / 4, 256, 0, stream>>>(
                hsrc[L], esrcs[L], excls[L], degs[L], aggb, nd);
            sage_gemm_mfma<256><<<(nd + 127) / 128, 512, 0, stream>>>(
                aggb, hsrc[L], Wlb[L], Wrb[L], gs[L], bs[L], hdst[L], nd);
        }
    }

    final_mfma<<<(ENDR + 127) / 128, 256, 0, stream>>>(
        h0b, h1b, h2b, wlinb, blin, out);
}